// Round 5
// baseline (361.249 us; speedup 1.0000x reference)
//
#include <hip/hip_runtime.h>

// Polar encoder: N=1024, K=512, BATCH=65536.
// Bit-packed butterfly: 32 uint32 words per row; one wave handles 2 rows
// (lanes 0-31 = row A words, lanes 32-63 = row B words), 8192 blocks.
// R5: inv map built once by a 1-block pre-kernel into d_ws -> main kernel
// has ZERO barriers (no vmcnt/lgkm drain points, no wave convoy).
// Staging loads issue first and flow into wave-private LDS.

#define PN     1024
#define PK     512
#define PBATCH 65536
#define WORDS  32   // PN/32

__global__ __launch_bounds__(256) void build_inv_kernel(
    const int* __restrict__ info_pos, int* __restrict__ inv)
{
    const int tid = threadIdx.x;
    #pragma unroll
    for (int i = tid; i < PN; i += 256) inv[i] = -1;
    __syncthreads();
    #pragma unroll
    for (int k = tid; k < PK; k += 256) inv[info_pos[k]] = k;
}

__global__ __launch_bounds__(256) void polar_encode_kernel(
    const float* __restrict__ u,
    const int*   __restrict__ ginv,   // [PN] in d_ws, prebuilt
    float*       __restrict__ out)
{
    __shared__ float su[4][2 * PK];   // per-wave staging: 2 rows of u

    const int tid  = threadIdx.x;
    const int lane = tid & 63;
    const int wave = tid >> 6;
    const int l31  = lane & 31;
    const int half = lane >> 5;                    // 0 = row A, 1 = row B
    const unsigned rA = blockIdx.x * 8u + wave * 2u;

    // --- issue staging loads FIRST (2 rows = 256 float4, 4 per lane)
    const float4* u4 = (const float4*)(u + (size_t)rA * PK);
    const float4 r0 = u4[       lane];
    const float4 r1 = u4[ 64 + lane];
    const float4 r2 = u4[128 + lane];
    const float4 r3 = u4[192 + lane];

    // wave-private LDS: no barrier needed (compiler inserts vmcnt/lgkm waits)
    float4* su4 = (float4*)su[wave];
    su4[       lane] = r0;
    su4[ 64 + lane] = r1;
    su4[128 + lane] = r2;
    su4[192 + lane] = r3;

    // --- gather + pack: round c builds codeword word c of both rows via
    // ballot. inv loads are global (4 KB, L1-hot, wave-uniform addresses
    // across blocks); branch-free clamp + mask.
    const float* srow = su[wave] + half * PK;
    unsigned int word = 0;
    #pragma unroll
    for (int c = 0; c < WORDS; ++c) {
        const int   iv  = ginv[c * 32 + l31];
        const float v   = srow[iv & (PK - 1)];
        const bool  bit = (iv >= 0) && (v != 0.0f);
        const unsigned long long m = __ballot(bit);
        const unsigned int sel =
            half ? (unsigned int)(m >> 32) : (unsigned int)m;
        if (l31 == c) word = sel;
    }

    // --- butterfly stages 0..4: bit distance 1,2,4,8,16 (in-word)
    word ^= (word >> 1)  & 0x55555555u;
    word ^= (word >> 2)  & 0x33333333u;
    word ^= (word >> 4)  & 0x0F0F0F0Fu;
    word ^= (word >> 8)  & 0x00FF00FFu;
    word ^= (word >> 16) & 0x0000FFFFu;

    // --- butterfly stages 5..9: word distance 1,2,4,8,16 (cross-lane;
    // off<=16 so lane^off stays within the 32-lane row half)
    #pragma unroll
    for (int off = 1; off <= 16; off <<= 1) {
        const unsigned int partner =
            (unsigned int)__shfl_xor((int)word, off, 64);
        if ((l31 & off) == 0) word ^= partner;
    }

    // --- coalesced float4 store (1 KiB per wave per instruction)
    float4* out4 = (float4*)out;
    const unsigned base = rA * (PN / 4);   // rA * 256
    #pragma unroll
    for (int j = 0; j < 8; ++j) {
        const int f   = j * 64 + lane;      // float4 index in the 2-row pair
        const int r   = f >> 8;             // row within pair
        const int wir = (f & 255) >> 3;     // word index within row
        const int src = wir + (r << 5);     // lane holding that word
        const unsigned int b   = (unsigned int)__shfl((int)word, src, 64);
        const unsigned int nib = (b >> ((lane & 7) * 4)) & 0xFu;
        float4 v4;
        v4.x = (nib & 1u) ? 1.0f : 0.0f;
        v4.y = (nib & 2u) ? 1.0f : 0.0f;
        v4.z = (nib & 4u) ? 1.0f : 0.0f;
        v4.w = (nib & 8u) ? 1.0f : 0.0f;
        out4[base + f] = v4;
    }
}

extern "C" void kernel_launch(void* const* d_in, const int* in_sizes, int n_in,
                              void* d_out, int out_size, void* d_ws, size_t ws_size,
                              hipStream_t stream) {
    const float* u        = (const float*)d_in[0];
    const int*   info_pos = (const int*)d_in[1];
    // d_in[2] = ind_gather — unused; butterfly structure is compiled in.
    float* out = (float*)d_out;
    int*   inv = (int*)d_ws;   // 4 KB scratch, rebuilt every call

    build_inv_kernel<<<1, 256, 0, stream>>>(info_pos, inv);
    // kernel boundary on the same stream orders + makes inv globally visible
    polar_encode_kernel<<<PBATCH / 8, 256, 0, stream>>>(u, inv, out);
}